// Round 1
// baseline (418.533 us; speedup 1.0000x reference)
//
#include <hip/hip_runtime.h>
#include <cstdint>
#include <cstddef>

// ---------- types ----------
typedef __attribute__((ext_vector_type(8))) __bf16 bf16x8;
typedef __attribute__((ext_vector_type(4))) __bf16 bf16x4;
typedef __attribute__((ext_vector_type(4))) float  f32x4;

#define MFMA_BF16(a, b, c) __builtin_amdgcn_mfma_f32_16x16x32_bf16((a), (b), (c), 0, 0, 0)

// async global->LDS, 16B per lane. LDS dest must be wave-uniform-base + lane*16.
__device__ __forceinline__ void gload_lds16(const __bf16* src, __bf16* lds_dst) {
    __builtin_amdgcn_global_load_lds(
        (const __attribute__((address_space(1))) void*)(const_cast<__bf16*>(src)),
        (__attribute__((address_space(3))) void*)(lds_dst), 16, 0, 0);
}

// ---------- fp32 -> bf16 convert ----------
__global__ __launch_bounds__(256) void cvt_kernel(const float* __restrict__ src,
                                                  __bf16* __restrict__ dst) {
    int i = blockIdx.x * 256 + threadIdx.x;
    float4 v = reinterpret_cast<const float4*>(src)[i];
    bf16x4 o;
    o[0] = (__bf16)v.x; o[1] = (__bf16)v.y; o[2] = (__bf16)v.z; o[3] = (__bf16)v.w;
    reinterpret_cast<bf16x4*>(dst)[i] = o;
}

// ---------- RMSNorm (row = 1024 fp32) -> bf16 ----------
__global__ __launch_bounds__(256) void rmsnorm_kernel(const float* __restrict__ x,
                                                      const float* __restrict__ g,
                                                      __bf16* __restrict__ out) {
    const int row = blockIdx.x;
    const int t = threadIdx.x;
    float4 v = reinterpret_cast<const float4*>(x + (size_t)row * 1024)[t];
    float ss = v.x * v.x + v.y * v.y + v.z * v.z + v.w * v.w;
#pragma unroll
    for (int m = 1; m < 64; m <<= 1) ss += __shfl_xor(ss, m);
    __shared__ float sred[4];
    if ((t & 63) == 0) sred[t >> 6] = ss;
    __syncthreads();
    float tot = sred[0] + sred[1] + sred[2] + sred[3];
    float rs = rsqrtf(tot * (1.0f / 1024.0f) + 1.1920928955078125e-07f);
    float4 gv = reinterpret_cast<const float4*>(g)[t];
    bf16x4 o;
    o[0] = (__bf16)(v.x * rs * gv.x);
    o[1] = (__bf16)(v.y * rs * gv.y);
    o[2] = (__bf16)(v.z * rs * gv.z);
    o[3] = (__bf16)(v.w * rs * gv.w);
    *reinterpret_cast<bf16x4*>(out + (size_t)row * 1024 + t * 4) = o;
}

// ---------- NT GEMM: C[m,n] = sum_k A[m,k] * B[n,k] ----------
// tile 128x128, BK=64, 4 waves (2x2), per-wave 64x64 = 4x4 frags of 16x16.
// MODE 0: out bf16 (ldo = N)
// MODE 1: out f32 = acc + resid (ldo = N)
// MODE 2: FFN1+SwiGLU fused: B-row n reads w1 row (n>>1) + (n&1)*4096 so that
//         even/odd output cols are (gate_j, up_j); epilogue pairs them via
//         shfl_xor(1) and stores silu(gate)*up at col>>1 (ldo = N/2).
template <int MODE>
__global__ __launch_bounds__(256) void gemm_nt(const __bf16* __restrict__ A, int lda,
                                               const __bf16* __restrict__ B, int ldb,
                                               __bf16* __restrict__ outb,
                                               float* __restrict__ outf,
                                               const float* __restrict__ resid,
                                               int K, int ldo) {
    __shared__ __attribute__((aligned(16))) __bf16 As[128 * 64];
    __shared__ __attribute__((aligned(16))) __bf16 Bs[128 * 64];
    const int t = threadIdx.x;
    const int lane = t & 63;
    const int wid = t >> 6;
    const int bm = blockIdx.x, bn = blockIdx.y;
    const int wm = (wid >> 1) * 64, wn = (wid & 1) * 64;
    f32x4 acc[4][4] = {};

    for (int kt = 0; kt < K; kt += 64) {
        __syncthreads();
        // stage A,B tiles: linear LDS dest, XOR-pre-swizzled global source chunk
#pragma unroll
        for (int i = 0; i < 4; ++i) {
            int L = i * 256 + t;      // 16B-chunk index
            int r = L >> 3, s = L & 7;
            int c = s ^ (r & 7);      // global chunk that lives in slot s
            const __bf16* sa = A + (size_t)(bm * 128 + r) * lda + kt + c * 8;
            gload_lds16(sa, As + L * 8);
            int rb = bn * 128 + r;
            int srow = (MODE == 2) ? ((rb >> 1) + ((rb & 1) << 12)) : rb;
            const __bf16* sb = B + (size_t)srow * ldb + kt + c * 8;
            gload_lds16(sb, Bs + L * 8);
        }
        __syncthreads();
#pragma unroll
        for (int ks = 0; ks < 2; ++ks) {
            bf16x8 af[4], bfr[4];
#pragma unroll
            for (int mi = 0; mi < 4; ++mi) {
                int r = wm + mi * 16 + (lane & 15);
                int slot = (ks * 4 + (lane >> 4)) ^ (r & 7);
                af[mi] = *reinterpret_cast<const bf16x8*>(As + r * 64 + slot * 8);
            }
#pragma unroll
            for (int ni = 0; ni < 4; ++ni) {
                int r = wn + ni * 16 + (lane & 15);
                int slot = (ks * 4 + (lane >> 4)) ^ (r & 7);
                bfr[ni] = *reinterpret_cast<const bf16x8*>(Bs + r * 64 + slot * 8);
            }
#pragma unroll
            for (int mi = 0; mi < 4; ++mi)
#pragma unroll
                for (int ni = 0; ni < 4; ++ni)
                    acc[mi][ni] = MFMA_BF16(af[mi], bfr[ni], acc[mi][ni]);
        }
    }
    // epilogue: C/D layout col = lane&15, row = (lane>>4)*4 + reg
    const int row0 = bm * 128 + wm + ((lane >> 4) << 2);
    const int col0 = bn * 128 + wn + (lane & 15);
#pragma unroll
    for (int mi = 0; mi < 4; ++mi)
#pragma unroll
        for (int ni = 0; ni < 4; ++ni)
#pragma unroll
            for (int r2 = 0; r2 < 4; ++r2) {
                int row = row0 + mi * 16 + r2;
                int col = col0 + ni * 16;
                float v = acc[mi][ni][r2];
                if (MODE == 0) {
                    outb[(size_t)row * ldo + col] = (__bf16)v;
                } else if (MODE == 1) {
                    size_t idx = (size_t)row * ldo + col;
                    outf[idx] = v + resid[idx];
                } else {
                    float pv = __shfl_xor(v, 1);   // partner column value
                    if (!(lane & 1)) {             // even lane holds gate, partner is up
                        float sg = v / (1.0f + __expf(-v));
                        outb[(size_t)row * ldo + (col >> 1)] = (__bf16)(sg * pv);
                    }
                }
            }
}

// ---------- flash attention, swapped-QK^T, per-wave 16 q-rows, KV tile 32 ----------
// qkv: [4096, 3072] bf16 (cols: [q | k | v], each h*64+hd). o: [4096, 1024] bf16.
__global__ __launch_bounds__(256) void attn_kernel(const __bf16* __restrict__ qkv,
                                                   __bf16* __restrict__ o) {
    __shared__ __attribute__((aligned(16))) __bf16 VT[64][40];      // V^T tile, pad 40
    __shared__ __attribute__((aligned(16))) __bf16 Pb[4][16][40];   // per-wave P
    const int t = threadIdx.x;
    const int lane = t & 63;
    const int w = t >> 6;
    const int g = lane >> 4;
    const int q16 = lane & 15;
    const int bh = blockIdx.y;
    const int b = bh >> 4, h = bh & 15;
    const __bf16* qp = qkv + (size_t)b * 2048 * 3072 + h * 64;
    const __bf16* kp = qp + 1024;
    const __bf16* vp = qp + 2048;
    const int q0 = blockIdx.x * 64 + w * 16;

    // Q fragments (B-operand): n = q row (q16), k = hd
    bf16x8 qf[2];
    {
        const size_t qrow = q0 + q16;
#pragma unroll
        for (int ki = 0; ki < 2; ++ki)
            qf[ki] = *reinterpret_cast<const bf16x8*>(qp + qrow * 3072 + ki * 32 + g * 8);
    }
    f32x4 oa[4] = {};
    float m_run = -INFINITY, l_run = 0.0f;
    const int vkr = t & 31, vhd0 = (t >> 5) * 8;

    for (int kt = 0; kt < 2048; kt += 32) {
        __syncthreads();   // prev PV done reading VT
        // stage V transposed: VT[hd][k]
        {
            bf16x8 vv = *reinterpret_cast<const bf16x8*>(vp + (size_t)(kt + vkr) * 3072 + vhd0);
#pragma unroll
            for (int j = 0; j < 8; ++j) VT[vhd0 + j][vkr] = vv[j];
        }
        // S^T = K_tile x Q : D col = q (q16), row = k ((lane>>4)*4+reg, +16*kbi)
        f32x4 st[2];
#pragma unroll
        for (int kbi = 0; kbi < 2; ++kbi) {
            f32x4 z = {};
#pragma unroll
            for (int ki = 0; ki < 2; ++ki) {
                bf16x8 kf = *reinterpret_cast<const bf16x8*>(
                    kp + (size_t)(kt + kbi * 16 + q16) * 3072 + ki * 32 + g * 8);
                z = MFMA_BF16(kf, qf[ki], z);
            }
            st[kbi] = z;
        }
        // online softmax over the q-row owned by this lane (q = q16)
        float mt = -INFINITY;
#pragma unroll
        for (int kbi = 0; kbi < 2; ++kbi)
#pragma unroll
            for (int r2 = 0; r2 < 4; ++r2) {
                st[kbi][r2] *= 0.125f;               // 1/sqrt(64)
                mt = fmaxf(mt, st[kbi][r2]);
            }
        mt = fmaxf(mt, __shfl_xor(mt, 16));
        mt = fmaxf(mt, __shfl_xor(mt, 32));
        const float m_new = fmaxf(m_run, mt);
        const float alpha = __expf(m_run - m_new);
        float ps = 0.0f;
        float pvv[8];
#pragma unroll
        for (int kbi = 0; kbi < 2; ++kbi)
#pragma unroll
            for (int r2 = 0; r2 < 4; ++r2) {
                float p = __expf(st[kbi][r2] - m_new);
                pvv[kbi * 4 + r2] = p;
                ps += p;
            }
        ps += __shfl_xor(ps, 16);
        ps += __shfl_xor(ps, 32);
        l_run = l_run * alpha + ps;
        m_run = m_new;
        // write P[q][k] (4 consecutive k per lane -> one 8B store)
#pragma unroll
        for (int kbi = 0; kbi < 2; ++kbi) {
            bf16x4 pw;
#pragma unroll
            for (int r2 = 0; r2 < 4; ++r2) pw[r2] = (__bf16)pvv[kbi * 4 + r2];
            *reinterpret_cast<bf16x4*>(&Pb[w][q16][kbi * 16 + g * 4]) = pw;
        }
        __syncthreads();   // VT visible
        // rescale O (O rows are q=(lane>>4)*4+reg -> fetch alpha via shfl)
#pragma unroll
        for (int r2 = 0; r2 < 4; ++r2) {
            float av = __shfl(alpha, g * 4 + r2);
#pragma unroll
            for (int ni = 0; ni < 4; ++ni) oa[ni][r2] *= av;
        }
        // PV: A = P (row=q16, k=seq), B = V^T rows (n=hd, k=seq)
        bf16x8 pa = *reinterpret_cast<const bf16x8*>(&Pb[w][q16][g * 8]);
#pragma unroll
        for (int ni = 0; ni < 4; ++ni) {
            bf16x8 vf = *reinterpret_cast<const bf16x8*>(&VT[ni * 16 + q16][g * 8]);
            oa[ni] = MFMA_BF16(pa, vf, oa[ni]);
        }
    }
    // finalize: divide by l, store bf16
#pragma unroll
    for (int r2 = 0; r2 < 4; ++r2) {
        float lv = __shfl(l_run, g * 4 + r2);
        float inv = 1.0f / lv;
        int row = q0 + g * 4 + r2;
#pragma unroll
        for (int ni = 0; ni < 4; ++ni) {
            int col = h * 64 + ni * 16 + q16;
            o[((size_t)b * 2048 + row) * 1024 + col] = (__bf16)(oa[ni][r2] * inv);
        }
    }
}

// ---------- launch ----------
extern "C" void kernel_launch(void* const* d_in, const int* in_sizes, int n_in,
                              void* d_out, int out_size, void* d_ws, size_t ws_size,
                              hipStream_t stream) {
    const float* x      = (const float*)d_in[0];
    // d_in[1] = t, d_in[2] = dt : unused by the reference
    const float* w_qkv  = (const float*)d_in[3];
    const float* w_o    = (const float*)d_in[4];
    const float* w1     = (const float*)d_in[5];
    const float* w2     = (const float*)d_in[6];
    const float* g_attn = (const float*)d_in[7];
    const float* g_ff   = (const float*)d_in[8];
    float* out = (float*)d_out;

    char* ws = (char*)d_ws;
    size_t off = 0;
    auto alloc = [&](size_t bytes) -> void* {
        void* p = ws + off;
        off += (bytes + 255) & ~(size_t)255;
        return p;
    };
    __bf16* wqkv_b = (__bf16*)alloc((size_t)3072 * 1024 * 2);
    __bf16* wo_b   = (__bf16*)alloc((size_t)1024 * 1024 * 2);
    __bf16* w1_b   = (__bf16*)alloc((size_t)8192 * 1024 * 2);
    __bf16* w2_b   = (__bf16*)alloc((size_t)1024 * 4096 * 2);
    __bf16* h_b    = (__bf16*)alloc((size_t)4096 * 1024 * 2);
    __bf16* qkv_b  = (__bf16*)alloc((size_t)4096 * 3072 * 2);   // 25165824 B (256-aligned)
    __bf16* o_b    = (__bf16*)alloc((size_t)4096 * 1024 * 2);
    float*  x2     = (float*)alloc((size_t)4096 * 1024 * 4);
    __bf16* act_b  = qkv_b;  // alias: act (33.55 MB) over [qkv|o] (dead after o-proj)

    // weights fp32 -> bf16
    cvt_kernel<<<3072, 256, 0, stream>>>(w_qkv, wqkv_b);
    cvt_kernel<<<1024, 256, 0, stream>>>(w_o, wo_b);
    cvt_kernel<<<8192, 256, 0, stream>>>(w1, w1_b);
    cvt_kernel<<<4096, 256, 0, stream>>>(w2, w2_b);

    // h = rms(x, g_attn); qkv = h @ w_qkv^T
    rmsnorm_kernel<<<4096, 256, 0, stream>>>(x, g_attn, h_b);
    gemm_nt<0><<<dim3(32, 24), 256, 0, stream>>>(h_b, 1024, wqkv_b, 1024,
                                                 qkv_b, nullptr, nullptr, 1024, 3072);
    // full attention (windowing is a permutation that cancels; RoPE discarded by ref)
    attn_kernel<<<dim3(32, 32), 256, 0, stream>>>(qkv_b, o_b);
    // x2 = x + o @ w_o^T
    gemm_nt<1><<<dim3(32, 8), 256, 0, stream>>>(o_b, 1024, wo_b, 1024,
                                                nullptr, x2, x, 1024, 1024);
    // hf = rms(x2, g_ff); act = silu(gate)*up fused in GEMM epilogue
    rmsnorm_kernel<<<4096, 256, 0, stream>>>(x2, g_ff, h_b);
    gemm_nt<2><<<dim3(32, 64), 256, 0, stream>>>(h_b, 1024, w1_b, 1024,
                                                 act_b, nullptr, nullptr, 1024, 4096);
    // out = x2 + act @ w2^T
    gemm_nt<1><<<dim3(32, 8), 256, 0, stream>>>(act_b, 4096, w2_b, 4096,
                                                nullptr, out, x2, 4096, 1024);
}

// Round 2
// 354.250 us; speedup vs baseline: 1.1815x; 1.1815x over previous
//
#include <hip/hip_runtime.h>
#include <cstdint>
#include <cstddef>

// ---------- types ----------
typedef __attribute__((ext_vector_type(8)))  __bf16 bf16x8;
typedef __attribute__((ext_vector_type(4)))  __bf16 bf16x4;
typedef __attribute__((ext_vector_type(4)))  float  f32x4;
typedef __attribute__((ext_vector_type(16))) float  f32x16;
typedef __attribute__((ext_vector_type(4)))  uint32_t u32x4;

#define MFMA_BF16(a, b, c) __builtin_amdgcn_mfma_f32_16x16x32_bf16((a), (b), (c), 0, 0, 0)
#define MFMA32(a, b, c)    __builtin_amdgcn_mfma_f32_32x32x16_bf16((a), (b), (c), 0, 0, 0)

// async global->LDS, 16B per lane. LDS dest must be wave-uniform base + lane*16.
__device__ __forceinline__ void gload_lds16(const __bf16* src, __bf16* lds_dst) {
    __builtin_amdgcn_global_load_lds(
        (const __attribute__((address_space(1))) void*)(const_cast<__bf16*>(src)),
        (__attribute__((address_space(3))) void*)(lds_dst), 16, 0, 0);
}

__device__ __forceinline__ uint32_t pack2(float a, float b) {
    uint16_t ua = __builtin_bit_cast(uint16_t, (__bf16)a);
    uint16_t ub = __builtin_bit_cast(uint16_t, (__bf16)b);
    return (uint32_t)ua | ((uint32_t)ub << 16);
}

// ---------- fp32 -> bf16 convert ----------
__global__ __launch_bounds__(256) void cvt_kernel(const float* __restrict__ src,
                                                  __bf16* __restrict__ dst) {
    int i = blockIdx.x * 256 + threadIdx.x;
    float4 v = reinterpret_cast<const float4*>(src)[i];
    bf16x4 o;
    o[0] = (__bf16)v.x; o[1] = (__bf16)v.y; o[2] = (__bf16)v.z; o[3] = (__bf16)v.w;
    reinterpret_cast<bf16x4*>(dst)[i] = o;
}

// ---------- RMSNorm (row = 1024 fp32) -> bf16 ----------
__global__ __launch_bounds__(256) void rmsnorm_kernel(const float* __restrict__ x,
                                                      const float* __restrict__ g,
                                                      __bf16* __restrict__ out) {
    const int row = blockIdx.x;
    const int t = threadIdx.x;
    float4 v = reinterpret_cast<const float4*>(x + (size_t)row * 1024)[t];
    float ss = v.x * v.x + v.y * v.y + v.z * v.z + v.w * v.w;
#pragma unroll
    for (int m = 1; m < 64; m <<= 1) ss += __shfl_xor(ss, m);
    __shared__ float sred[4];
    if ((t & 63) == 0) sred[t >> 6] = ss;
    __syncthreads();
    float tot = sred[0] + sred[1] + sred[2] + sred[3];
    float rs = rsqrtf(tot * (1.0f / 1024.0f) + 1.1920928955078125e-07f);
    float4 gv = reinterpret_cast<const float4*>(g)[t];
    bf16x4 o;
    o[0] = (__bf16)(v.x * rs * gv.x);
    o[1] = (__bf16)(v.y * rs * gv.y);
    o[2] = (__bf16)(v.z * rs * gv.z);
    o[3] = (__bf16)(v.w * rs * gv.w);
    *reinterpret_cast<bf16x4*>(out + (size_t)row * 1024 + t * 4) = o;
}

// ---------- NT GEMM: C[m,n] = sum_k A[m,k] * B[n,k] ----------
// tile 128x128, BK=64, 4 waves (2x2), per-wave 64x64 = 4x4 frags of 16x16.
// MODE 0: out bf16 (ldo = N)
// MODE 1: out f32 = acc + resid (ldo = N)
// MODE 2: FFN1+SwiGLU fused (see launch).
template <int MODE>
__global__ __launch_bounds__(256) void gemm_nt(const __bf16* __restrict__ A, int lda,
                                               const __bf16* __restrict__ B, int ldb,
                                               __bf16* __restrict__ outb,
                                               float* __restrict__ outf,
                                               const float* __restrict__ resid,
                                               int K, int ldo) {
    __shared__ __attribute__((aligned(16))) __bf16 As[128 * 64];
    __shared__ __attribute__((aligned(16))) __bf16 Bs[128 * 64];
    const int t = threadIdx.x;
    const int lane = t & 63;
    const int wid = t >> 6;
    const int bm = blockIdx.x, bn = blockIdx.y;
    const int wm = (wid >> 1) * 64, wn = (wid & 1) * 64;
    f32x4 acc[4][4] = {};

    for (int kt = 0; kt < K; kt += 64) {
        __syncthreads();
#pragma unroll
        for (int i = 0; i < 4; ++i) {
            int L = i * 256 + t;      // 16B-chunk index
            int r = L >> 3, s = L & 7;
            int c = s ^ (r & 7);      // global chunk that lives in slot s
            const __bf16* sa = A + (size_t)(bm * 128 + r) * lda + kt + c * 8;
            gload_lds16(sa, As + L * 8);
            int rb = bn * 128 + r;
            int srow = (MODE == 2) ? ((rb >> 1) + ((rb & 1) << 12)) : rb;
            const __bf16* sb = B + (size_t)srow * ldb + kt + c * 8;
            gload_lds16(sb, Bs + L * 8);
        }
        __syncthreads();
#pragma unroll
        for (int ks = 0; ks < 2; ++ks) {
            bf16x8 af[4], bfr[4];
#pragma unroll
            for (int mi = 0; mi < 4; ++mi) {
                int r = wm + mi * 16 + (lane & 15);
                int slot = (ks * 4 + (lane >> 4)) ^ (r & 7);
                af[mi] = *reinterpret_cast<const bf16x8*>(As + r * 64 + slot * 8);
            }
#pragma unroll
            for (int ni = 0; ni < 4; ++ni) {
                int r = wn + ni * 16 + (lane & 15);
                int slot = (ks * 4 + (lane >> 4)) ^ (r & 7);
                bfr[ni] = *reinterpret_cast<const bf16x8*>(Bs + r * 64 + slot * 8);
            }
#pragma unroll
            for (int mi = 0; mi < 4; ++mi)
#pragma unroll
                for (int ni = 0; ni < 4; ++ni)
                    acc[mi][ni] = MFMA_BF16(af[mi], bfr[ni], acc[mi][ni]);
        }
    }
    const int row0 = bm * 128 + wm + ((lane >> 4) << 2);
    const int col0 = bn * 128 + wn + (lane & 15);
#pragma unroll
    for (int mi = 0; mi < 4; ++mi)
#pragma unroll
        for (int ni = 0; ni < 4; ++ni)
#pragma unroll
            for (int r2 = 0; r2 < 4; ++r2) {
                int row = row0 + mi * 16 + r2;
                int col = col0 + ni * 16;
                float v = acc[mi][ni][r2];
                if (MODE == 0) {
                    outb[(size_t)row * ldo + col] = (__bf16)v;
                } else if (MODE == 1) {
                    size_t idx = (size_t)row * ldo + col;
                    outf[idx] = v + resid[idx];
                } else {
                    float pv = __shfl_xor(v, 1);
                    if (!(lane & 1)) {
                        float sg = v / (1.0f + __expf(-v));
                        outb[(size_t)row * ldo + (col >> 1)] = (__bf16)(sg * pv);
                    }
                }
            }
}

// ---------- V transpose: qkv V block [n][hd] -> vt [bh][hd][n] ----------
__global__ __launch_bounds__(256) void vtrans_kernel(const __bf16* __restrict__ qkv,
                                                     __bf16* __restrict__ vt) {
    __shared__ __bf16 T[64][68];   // pad 68: scatter-write banks spread, rows != 0 mod 128B
    const int t = threadIdx.x;
    const int bh = blockIdx.y, b = bh >> 4, h = bh & 15;
    const int n0 = blockIdx.x * 64;
    const __bf16* vp = qkv + (size_t)b * 2048 * 3072 + 2048 + h * 64;
#pragma unroll
    for (int i = 0; i < 2; ++i) {
        int r = i * 32 + (t >> 3), c = t & 7;            // n-row, hd-chunk
        bf16x8 v = *reinterpret_cast<const bf16x8*>(vp + (size_t)(n0 + r) * 3072 + c * 8);
#pragma unroll
        for (int j = 0; j < 8; ++j) T[c * 8 + j][r] = v[j];   // scatter: T[hd][n]
    }
    __syncthreads();
#pragma unroll
    for (int i = 0; i < 2; ++i) {
        int hd = i * 32 + (t >> 3), c = t & 7;           // hd-row, n-chunk
        bf16x8 v;
#pragma unroll
        for (int j = 0; j < 8; ++j) v[j] = T[hd][c * 8 + j];
        *reinterpret_cast<bf16x8*>(vt + ((size_t)bh * 64 + hd) * 2048 + n0 + c * 8) = v;
    }
}

// ---------- flash attention v2 ----------
// 4 waves x 32 q-rows, KVBLK=64, 32x32x16 MFMA, swapped QK^T, in-register P.
// qkv: [4096,3072] bf16; vt: [32][64][2048] bf16; o: [4096,1024] bf16.
__global__ __launch_bounds__(256) void attn_kernel(const __bf16* __restrict__ qkv,
                                                   const __bf16* __restrict__ vt,
                                                   __bf16* __restrict__ o) {
    __shared__ __attribute__((aligned(16))) __bf16 Ks[2][64 * 64];
    __shared__ __attribute__((aligned(16))) __bf16 Vs[2][64 * 64];
    const int t = threadIdx.x;
    const int lane = t & 63;
    const int w = t >> 6;
    const int hi = lane >> 5;
    const int l31 = lane & 31;
    const int bh = blockIdx.y;
    const int b = bh >> 4, h = bh & 15;
    const __bf16* qp = qkv + (size_t)b * 2048 * 3072 + h * 64;
    const __bf16* kp = qp + 1024;
    const __bf16* vtp = vt + (size_t)bh * 64 * 2048;
    const int q0 = blockIdx.x * 128 + w * 32;

    // Q fragments (B-operand: col=q=lane&31, k=hd), pre-scaled by 1/8*log2(e)
    const float SC = 0.18033688011112042f;
    bf16x8 qf[4];
#pragma unroll
    for (int s = 0; s < 4; ++s) {
        bf16x8 raw = *reinterpret_cast<const bf16x8*>(
            qp + (size_t)(q0 + l31) * 3072 + s * 16 + hi * 8);
        bf16x8 sc;
#pragma unroll
        for (int j = 0; j < 8; ++j) sc[j] = (__bf16)((float)raw[j] * SC);
        qf[s] = sc;
    }

    f32x16 oa[2] = {};
    float m_run = -INFINITY, l_run = 0.0f;

    auto stage = [&](int buf, int kt) {
#pragma unroll
        for (int i = 0; i < 2; ++i) {
            int L = i * 256 + t;
            int r = L >> 3, s = L & 7;
            int c = s ^ (r & 7);   // pre-swizzled source chunk, linear LDS dest
            gload_lds16(kp + (size_t)(kt + r) * 3072 + c * 8, &Ks[buf][L * 8]);
            gload_lds16(vtp + (size_t)r * 2048 + kt + c * 8, &Vs[buf][L * 8]);
        }
    };
    stage(0, 0);
    __syncthreads();

    for (int kt = 0; kt < 2048; kt += 64) {
        const int buf = (kt >> 6) & 1;
        if (kt + 64 < 2048) stage(buf ^ 1, kt + 64);

        // S^T = K_tile x Q : D col = q (l31), row = k_seq
        f32x16 st[2] = {};
#pragma unroll
        for (int s = 0; s < 4; ++s) {
#pragma unroll
            for (int mb = 0; mb < 2; ++mb) {
                int r = mb * 32 + l31;
                int sl = (s * 2 + hi) ^ (r & 7);
                bf16x8 kf = *reinterpret_cast<const bf16x8*>(&Ks[buf][r * 64 + sl * 8]);
                st[mb] = MFMA32(kf, qf[s], st[mb]);
            }
        }
        // online softmax in log2 domain; lane owns q=l31 (its hi half of k-rows)
        float mt = -INFINITY;
#pragma unroll
        for (int mb = 0; mb < 2; ++mb)
#pragma unroll
            for (int r = 0; r < 16; ++r) mt = fmaxf(mt, st[mb][r]);
        mt = fmaxf(mt, __shfl_xor(mt, 32));
        const float m_new = fmaxf(m_run, mt);
        const float alpha = exp2f(m_run - m_new);
        float ps = 0.0f;
#pragma unroll
        for (int mb = 0; mb < 2; ++mb)
#pragma unroll
            for (int r = 0; r < 16; ++r) {
                float p = exp2f(st[mb][r] - m_new);
                st[mb][r] = p;
                ps += p;
            }
        ps += __shfl_xor(ps, 32);
        l_run = l_run * alpha + ps;
        m_run = m_new;

        // rescale O (rows are q = (r&3)+8*(r>>2)+4*hi)
#pragma unroll
        for (int r = 0; r < 16; ++r) {
            float av = __shfl(alpha, (r & 3) + 8 * (r >> 2) + 4 * hi);
            oa[0][r] *= av;
            oa[1][r] *= av;
        }

        // pack P to bf16 pairs; partner halves via shfl_xor(32)
        uint32_t pk[16], qk[16];
#pragma unroll
        for (int mb = 0; mb < 2; ++mb)
#pragma unroll
            for (int i2 = 0; i2 < 8; ++i2)
                pk[mb * 8 + i2] = pack2(st[mb][2 * i2], st[mb][2 * i2 + 1]);
#pragma unroll
        for (int i2 = 0; i2 < 16; ++i2)
            qk[i2] = (uint32_t)__shfl_xor((int)pk[i2], 32);

        // PV: A = P (row=q=l31, k=seq), B = V^T rows (col=hd, k=seq)
#pragma unroll
        for (int s2 = 0; s2 < 4; ++s2) {
            int mb = s2 >> 1, sl2 = s2 & 1;
            u32x4 fv;
            if (hi == 0) {
                fv[0] = pk[mb * 8 + 4 * sl2 + 0]; fv[1] = pk[mb * 8 + 4 * sl2 + 1];
                fv[2] = qk[mb * 8 + 4 * sl2 + 0]; fv[3] = qk[mb * 8 + 4 * sl2 + 1];
            } else {
                fv[0] = qk[mb * 8 + 4 * sl2 + 2]; fv[1] = qk[mb * 8 + 4 * sl2 + 3];
                fv[2] = pk[mb * 8 + 4 * sl2 + 2]; fv[3] = pk[mb * 8 + 4 * sl2 + 3];
            }
            bf16x8 pa = __builtin_bit_cast(bf16x8, fv);
#pragma unroll
            for (int nb = 0; nb < 2; ++nb) {
                int rv = nb * 32 + l31;
                int sl = (s2 * 2 + hi) ^ (rv & 7);
                bf16x8 vf = *reinterpret_cast<const bf16x8*>(&Vs[buf][rv * 64 + sl * 8]);
                oa[nb] = MFMA32(pa, vf, oa[nb]);
            }
        }
        __syncthreads();   // all waves done with buf; staged buf^1 visible
    }

    // finalize: divide by l, store
#pragma unroll
    for (int r = 0; r < 16; ++r) {
        int crow = (r & 3) + 8 * (r >> 2) + 4 * hi;
        float lv = __shfl(l_run, crow);
        float inv = 1.0f / lv;
        int row = q0 + crow;
        size_t base = ((size_t)b * 2048 + row) * 1024 + h * 64 + l31;
        o[base]      = (__bf16)(oa[0][r] * inv);
        o[base + 32] = (__bf16)(oa[1][r] * inv);
    }
}

// ---------- launch ----------
extern "C" void kernel_launch(void* const* d_in, const int* in_sizes, int n_in,
                              void* d_out, int out_size, void* d_ws, size_t ws_size,
                              hipStream_t stream) {
    const float* x      = (const float*)d_in[0];
    const float* w_qkv  = (const float*)d_in[3];
    const float* w_o    = (const float*)d_in[4];
    const float* w1     = (const float*)d_in[5];
    const float* w2     = (const float*)d_in[6];
    const float* g_attn = (const float*)d_in[7];
    const float* g_ff   = (const float*)d_in[8];
    float* out = (float*)d_out;

    char* ws = (char*)d_ws;
    size_t off = 0;
    auto alloc = [&](size_t bytes) -> void* {
        void* p = ws + off;
        off += (bytes + 255) & ~(size_t)255;
        return p;
    };
    __bf16* wqkv_b = (__bf16*)alloc((size_t)3072 * 1024 * 2);
    __bf16* wo_b   = (__bf16*)alloc((size_t)1024 * 1024 * 2);
    __bf16* w1_b   = (__bf16*)alloc((size_t)8192 * 1024 * 2);
    __bf16* w2_b   = (__bf16*)alloc((size_t)1024 * 4096 * 2);
    __bf16* h_b    = (__bf16*)alloc((size_t)4096 * 1024 * 2);
    __bf16* qkv_b  = (__bf16*)alloc((size_t)4096 * 3072 * 2);
    __bf16* o_b    = (__bf16*)alloc((size_t)4096 * 1024 * 2);
    float*  x2     = (float*)alloc((size_t)4096 * 1024 * 4);
    __bf16* vt_b   = (__bf16*)alloc((size_t)32 * 64 * 2048 * 2);
    __bf16* act_b  = qkv_b;  // alias: act over [qkv|o] (dead after o-proj)

    cvt_kernel<<<3072, 256, 0, stream>>>(w_qkv, wqkv_b);
    cvt_kernel<<<1024, 256, 0, stream>>>(w_o, wo_b);
    cvt_kernel<<<8192, 256, 0, stream>>>(w1, w1_b);
    cvt_kernel<<<4096, 256, 0, stream>>>(w2, w2_b);

    rmsnorm_kernel<<<4096, 256, 0, stream>>>(x, g_attn, h_b);
    gemm_nt<0><<<dim3(32, 24), 256, 0, stream>>>(h_b, 1024, wqkv_b, 1024,
                                                 qkv_b, nullptr, nullptr, 1024, 3072);
    vtrans_kernel<<<dim3(32, 32), 256, 0, stream>>>(qkv_b, vt_b);
    attn_kernel<<<dim3(16, 32), 256, 0, stream>>>(qkv_b, vt_b, o_b);
    gemm_nt<1><<<dim3(32, 8), 256, 0, stream>>>(o_b, 1024, wo_b, 1024,
                                                nullptr, x2, x, 1024, 1024);
    rmsnorm_kernel<<<4096, 256, 0, stream>>>(x2, g_ff, h_b);
    gemm_nt<2><<<dim3(32, 64), 256, 0, stream>>>(h_b, 1024, w1_b, 1024,
                                                 act_b, nullptr, nullptr, 1024, 4096);
    gemm_nt<1><<<dim3(32, 8), 256, 0, stream>>>(act_b, 4096, w2_b, 4096,
                                                nullptr, out, x2, 4096, 1024);
}

// Round 3
// 320.224 us; speedup vs baseline: 1.3070x; 1.1063x over previous
//
#include <hip/hip_runtime.h>
#include <cstdint>
#include <cstddef>

// ---------- types ----------
typedef __attribute__((ext_vector_type(8)))  __bf16 bf16x8;
typedef __attribute__((ext_vector_type(4)))  __bf16 bf16x4;
typedef __attribute__((ext_vector_type(4)))  float  f32x4;
typedef __attribute__((ext_vector_type(16))) float  f32x16;
typedef __attribute__((ext_vector_type(2)))  uint32_t u32x2;
typedef __attribute__((ext_vector_type(4)))  uint32_t u32x4;

#define MFMA_BF16(a, b, c) __builtin_amdgcn_mfma_f32_16x16x32_bf16((a), (b), (c), 0, 0, 0)
#define MFMA32(a, b, c)    __builtin_amdgcn_mfma_f32_32x32x16_bf16((a), (b), (c), 0, 0, 0)

// async global->LDS, 16B per lane. LDS dest must be wave-uniform base + lane*16.
__device__ __forceinline__ void gload_lds16(const __bf16* src, __bf16* lds_dst) {
    __builtin_amdgcn_global_load_lds(
        (const __attribute__((address_space(1))) void*)(const_cast<__bf16*>(src)),
        (__attribute__((address_space(3))) void*)(lds_dst), 16, 0, 0);
}

__device__ __forceinline__ uint32_t pack2(float a, float b) {
    uint16_t ua = __builtin_bit_cast(uint16_t, (__bf16)a);
    uint16_t ub = __builtin_bit_cast(uint16_t, (__bf16)b);
    return (uint32_t)ua | ((uint32_t)ub << 16);
}

// ---------- fp32 -> bf16 convert ----------
__global__ __launch_bounds__(256) void cvt_kernel(const float* __restrict__ src,
                                                  __bf16* __restrict__ dst) {
    int i = blockIdx.x * 256 + threadIdx.x;
    float4 v = reinterpret_cast<const float4*>(src)[i];
    bf16x4 o;
    o[0] = (__bf16)v.x; o[1] = (__bf16)v.y; o[2] = (__bf16)v.z; o[3] = (__bf16)v.w;
    reinterpret_cast<bf16x4*>(dst)[i] = o;
}

// ---------- RMSNorm (row = 1024 fp32) -> bf16 ----------
__global__ __launch_bounds__(256) void rmsnorm_kernel(const float* __restrict__ x,
                                                      const float* __restrict__ g,
                                                      __bf16* __restrict__ out) {
    const int row = blockIdx.x;
    const int t = threadIdx.x;
    float4 v = reinterpret_cast<const float4*>(x + (size_t)row * 1024)[t];
    float ss = v.x * v.x + v.y * v.y + v.z * v.z + v.w * v.w;
#pragma unroll
    for (int m = 1; m < 64; m <<= 1) ss += __shfl_xor(ss, m);
    __shared__ float sred[4];
    if ((t & 63) == 0) sred[t >> 6] = ss;
    __syncthreads();
    float tot = sred[0] + sred[1] + sred[2] + sred[3];
    float rs = rsqrtf(tot * (1.0f / 1024.0f) + 1.1920928955078125e-07f);
    float4 gv = reinterpret_cast<const float4*>(g)[t];
    bf16x4 o;
    o[0] = (__bf16)(v.x * rs * gv.x);
    o[1] = (__bf16)(v.y * rs * gv.y);
    o[2] = (__bf16)(v.z * rs * gv.z);
    o[3] = (__bf16)(v.w * rs * gv.w);
    *reinterpret_cast<bf16x4*>(out + (size_t)row * 1024 + t * 4) = o;
}

// ---------- NT GEMM: C[m,n] = sum_k A[m,k] * B[n,k] ----------
// tile 128 x (NB*32), BK=64, 4 waves (2x2): per-wave 64 x (NB*16).
// MODE 0: out bf16. MODE 1: out f32 = acc + resid. MODE 2: FFN1+SwiGLU fused.
template <int MODE, int NB>
__global__ __launch_bounds__(256) void gemm_nt(const __bf16* __restrict__ A, int lda,
                                               const __bf16* __restrict__ B, int ldb,
                                               __bf16* __restrict__ outb,
                                               float* __restrict__ outf,
                                               const float* __restrict__ resid,
                                               int K, int ldo) {
    constexpr int BN = NB * 32;
    __shared__ __attribute__((aligned(16))) __bf16 As[128 * 64];
    __shared__ __attribute__((aligned(16))) __bf16 Bs[BN * 64];
    const int t = threadIdx.x;
    const int lane = t & 63;
    const int wid = t >> 6;
    const int bm = blockIdx.x, bn = blockIdx.y;
    const int wm = (wid >> 1) * 64, wn = (wid & 1) * (NB * 16);
    f32x4 acc[4][NB] = {};

    for (int kt = 0; kt < K; kt += 64) {
        __syncthreads();
#pragma unroll
        for (int i = 0; i < 4; ++i) {   // A tile: 128x64
            int L = i * 256 + t;
            int r = L >> 3, s = L & 7;
            int c = s ^ (r & 7);
            gload_lds16(A + (size_t)(bm * 128 + r) * lda + kt + c * 8, As + L * 8);
        }
#pragma unroll
        for (int i = 0; i < NB; ++i) {  // B tile: BNx64
            int L = i * 256 + t;
            int r = L >> 3, s = L & 7;
            int c = s ^ (r & 7);
            int rb = bn * BN + r;
            int srow = (MODE == 2) ? ((rb >> 1) + ((rb & 1) << 12)) : rb;
            gload_lds16(B + (size_t)srow * ldb + kt + c * 8, Bs + L * 8);
        }
        __syncthreads();
#pragma unroll
        for (int ks = 0; ks < 2; ++ks) {
            bf16x8 af[4], bfr[NB];
#pragma unroll
            for (int mi = 0; mi < 4; ++mi) {
                int r = wm + mi * 16 + (lane & 15);
                int slot = (ks * 4 + (lane >> 4)) ^ (r & 7);
                af[mi] = *reinterpret_cast<const bf16x8*>(As + r * 64 + slot * 8);
            }
#pragma unroll
            for (int ni = 0; ni < NB; ++ni) {
                int r = wn + ni * 16 + (lane & 15);
                int slot = (ks * 4 + (lane >> 4)) ^ (r & 7);
                bfr[ni] = *reinterpret_cast<const bf16x8*>(Bs + r * 64 + slot * 8);
            }
#pragma unroll
            for (int mi = 0; mi < 4; ++mi)
#pragma unroll
                for (int ni = 0; ni < NB; ++ni)
                    acc[mi][ni] = MFMA_BF16(af[mi], bfr[ni], acc[mi][ni]);
        }
    }
    const int row0 = bm * 128 + wm + ((lane >> 4) << 2);
    const int col0 = bn * BN + wn + (lane & 15);
#pragma unroll
    for (int mi = 0; mi < 4; ++mi)
#pragma unroll
        for (int ni = 0; ni < NB; ++ni)
#pragma unroll
            for (int r2 = 0; r2 < 4; ++r2) {
                int row = row0 + mi * 16 + r2;
                int col = col0 + ni * 16;
                float v = acc[mi][ni][r2];
                if (MODE == 0) {
                    outb[(size_t)row * ldo + col] = (__bf16)v;
                } else if (MODE == 1) {
                    size_t idx = (size_t)row * ldo + col;
                    outf[idx] = v + resid[idx];
                } else {
                    float pv = __shfl_xor(v, 1);
                    if (!(lane & 1)) {
                        float sg = v / (1.0f + __expf(-v));
                        outb[(size_t)row * ldo + (col >> 1)] = (__bf16)(sg * pv);
                    }
                }
            }
}

// ---------- V transpose: qkv V block [n][hd] -> vt [bh][hd][n] ----------
__global__ __launch_bounds__(256) void vtrans_kernel(const __bf16* __restrict__ qkv,
                                                     __bf16* __restrict__ vt) {
    __shared__ __bf16 T[64][68];
    const int t = threadIdx.x;
    const int bh = blockIdx.y, b = bh >> 4, h = bh & 15;
    const int n0 = blockIdx.x * 64;
    const __bf16* vp = qkv + (size_t)b * 2048 * 3072 + 2048 + h * 64;
#pragma unroll
    for (int i = 0; i < 2; ++i) {
        int r = i * 32 + (t >> 3), c = t & 7;
        bf16x8 v = *reinterpret_cast<const bf16x8*>(vp + (size_t)(n0 + r) * 3072 + c * 8);
#pragma unroll
        for (int j = 0; j < 8; ++j) T[c * 8 + j][r] = v[j];
    }
    __syncthreads();
#pragma unroll
    for (int i = 0; i < 2; ++i) {
        int hd = i * 32 + (t >> 3), c = t & 7;
        bf16x8 v;
#pragma unroll
        for (int j = 0; j < 8; ++j) v[j] = T[hd][c * 8 + j];
        *reinterpret_cast<bf16x8*>(vt + ((size_t)bh * 64 + hd) * 2048 + n0 + c * 8) = v;
    }
}

// ---------- flash attention v3 ----------
// 4 waves x 32 q-rows, KVBLK=128 (2 x 64-halves), 32x32x16 MFMA, swapped QK^T,
// in-register P via permlane32_swap, defer-max rescale, exp2 domain.
__global__ __launch_bounds__(256) void attn_kernel(const __bf16* __restrict__ qkv,
                                                   const __bf16* __restrict__ vt,
                                                   __bf16* __restrict__ o) {
    __shared__ __attribute__((aligned(16))) __bf16 Ks[2][128 * 64];
    __shared__ __attribute__((aligned(16))) __bf16 Vs[2][64 * 128];
    const int t = threadIdx.x;
    const int lane = t & 63;
    const int w = t >> 6;
    const int hi = lane >> 5;
    const int l31 = lane & 31;
    const int bh = blockIdx.y;
    const int b = bh >> 4, h = bh & 15;
    const __bf16* qp = qkv + (size_t)b * 2048 * 3072 + h * 64;
    const __bf16* kp = qp + 1024;
    const __bf16* vtp = vt + (size_t)bh * 64 * 2048;
    const int q0 = blockIdx.x * 128 + w * 32;

    // Q fragments (B-operand: col=q=lane&31, k=hd), pre-scaled by 1/8*log2(e)
    const float SC = 0.18033688011112042f;
    bf16x8 qf[4];
#pragma unroll
    for (int s = 0; s < 4; ++s) {
        bf16x8 raw = *reinterpret_cast<const bf16x8*>(
            qp + (size_t)(q0 + l31) * 3072 + s * 16 + hi * 8);
        bf16x8 sc;
#pragma unroll
        for (int j = 0; j < 8; ++j) sc[j] = (__bf16)((float)raw[j] * SC);
        qf[s] = sc;
    }

    f32x16 oa[2] = {};
    float m_run = -INFINITY, l_run = 0.0f;

    auto stage = [&](int buf, int kt) {
#pragma unroll
        for (int i = 0; i < 4; ++i) {   // K: 128 rows x 64 hd
            int L = i * 256 + t;
            int r = L >> 3, s = L & 7;
            int c = s ^ (r & 7);
            gload_lds16(kp + (size_t)(kt + r) * 3072 + c * 8, &Ks[buf][L * 8]);
        }
#pragma unroll
        for (int i = 0; i < 4; ++i) {   // V^T: 64 hd x 128 seq
            int L = i * 256 + t;
            int r = L >> 4, s = L & 15;
            int c = s ^ (r & 15);
            gload_lds16(vtp + (size_t)r * 2048 + kt + c * 8, &Vs[buf][L * 8]);
        }
    };
    stage(0, 0);
    __syncthreads();

    for (int kt = 0; kt < 2048; kt += 128) {
        const int buf = (kt >> 7) & 1;
        if (kt + 128 < 2048) stage(buf ^ 1, kt + 128);

#pragma unroll
        for (int h2 = 0; h2 < 2; ++h2) {
            // S^T = K_half x Q : D col = q (l31), row(reg) = k_local
            f32x16 st[2] = {};
#pragma unroll
            for (int s = 0; s < 4; ++s) {
#pragma unroll
                for (int mb = 0; mb < 2; ++mb) {
                    int r = h2 * 64 + mb * 32 + l31;
                    int sl = (s * 2 + hi) ^ (r & 7);
                    bf16x8 kf = *reinterpret_cast<const bf16x8*>(&Ks[buf][r * 64 + sl * 8]);
                    st[mb] = MFMA32(kf, qf[s], st[mb]);
                }
            }
            // online softmax (log2 domain), lane owns q = l31 (hi-half of k rows)
            float mt = -INFINITY;
#pragma unroll
            for (int mb = 0; mb < 2; ++mb)
#pragma unroll
                for (int r = 0; r < 16; ++r) mt = fmaxf(mt, st[mb][r]);
            mt = fmaxf(mt, __shfl_xor(mt, 32));
            if (__any(mt > m_run + 8.0f)) {        // defer-max: rescale rarely
                float m_new = fmaxf(m_run, mt);
                float alpha = exp2f(m_run - m_new);
#pragma unroll
                for (int r = 0; r < 16; ++r) {
                    float av = __shfl(alpha, (r & 3) + 8 * (r >> 2) + 4 * hi);
                    oa[0][r] *= av;
                    oa[1][r] *= av;
                }
                l_run *= alpha;
                m_run = m_new;
            }
            float ps = 0.0f;
#pragma unroll
            for (int mb = 0; mb < 2; ++mb)
#pragma unroll
                for (int r = 0; r < 16; ++r) {
                    float p = exp2f(st[mb][r] - m_run);
                    st[mb][r] = p;
                    ps += p;
                }
            ps += __shfl_xor(ps, 32);
            l_run += ps;

            // pack P to bf16 pairs (k ascending within each pk word)
            uint32_t pk[16];
#pragma unroll
            for (int mb = 0; mb < 2; ++mb)
#pragma unroll
                for (int i2 = 0; i2 < 8; ++i2)
                    pk[mb * 8 + i2] = pack2(st[mb][2 * i2], st[mb][2 * i2 + 1]);

            // PV: A-fragment words via permlane32_swap (no divergence, 2 swaps/MFMA)
#pragma unroll
            for (int s2 = 0; s2 < 4; ++s2) {
                const int I0 = (s2 >> 1) * 8 + (s2 & 1) * 4;
                u32x2 w02 = __builtin_amdgcn_permlane32_swap(pk[I0], pk[I0 + 2], false, false);
                u32x2 w13 = __builtin_amdgcn_permlane32_swap(pk[I0 + 1], pk[I0 + 3], false, false);
                u32x4 fv;
                fv[0] = w02[0]; fv[1] = w13[0]; fv[2] = w02[1]; fv[3] = w13[1];
                bf16x8 pa = __builtin_bit_cast(bf16x8, fv);
#pragma unroll
                for (int nb = 0; nb < 2; ++nb) {
                    int rv = nb * 32 + l31;
                    int ch = h2 * 8 + s2 * 2 + hi;
                    int sl = ch ^ (rv & 15);
                    bf16x8 vf = *reinterpret_cast<const bf16x8*>(&Vs[buf][rv * 128 + sl * 8]);
                    oa[nb] = MFMA32(pa, vf, oa[nb]);
                }
            }
        }
        __syncthreads();   // all waves done with buf; staged buf^1 ready next iter
    }

    // finalize: divide by l, store
#pragma unroll
    for (int r = 0; r < 16; ++r) {
        int crow = (r & 3) + 8 * (r >> 2) + 4 * hi;
        float lv = __shfl(l_run, crow);
        float inv = 1.0f / lv;
        int row = q0 + crow;
        size_t base = ((size_t)b * 2048 + row) * 1024 + h * 64 + l31;
        o[base]      = (__bf16)(oa[0][r] * inv);
        o[base + 32] = (__bf16)(oa[1][r] * inv);
    }
}

// ---------- launch ----------
extern "C" void kernel_launch(void* const* d_in, const int* in_sizes, int n_in,
                              void* d_out, int out_size, void* d_ws, size_t ws_size,
                              hipStream_t stream) {
    const float* x      = (const float*)d_in[0];
    const float* w_qkv  = (const float*)d_in[3];
    const float* w_o    = (const float*)d_in[4];
    const float* w1     = (const float*)d_in[5];
    const float* w2     = (const float*)d_in[6];
    const float* g_attn = (const float*)d_in[7];
    const float* g_ff   = (const float*)d_in[8];
    float* out = (float*)d_out;

    char* ws = (char*)d_ws;
    size_t off = 0;
    auto alloc = [&](size_t bytes) -> void* {
        void* p = ws + off;
        off += (bytes + 255) & ~(size_t)255;
        return p;
    };
    __bf16* wqkv_b = (__bf16*)alloc((size_t)3072 * 1024 * 2);
    __bf16* wo_b   = (__bf16*)alloc((size_t)1024 * 1024 * 2);
    __bf16* w1_b   = (__bf16*)alloc((size_t)8192 * 1024 * 2);
    __bf16* w2_b   = (__bf16*)alloc((size_t)1024 * 4096 * 2);
    __bf16* h_b    = (__bf16*)alloc((size_t)4096 * 1024 * 2);
    __bf16* qkv_b  = (__bf16*)alloc((size_t)4096 * 3072 * 2);
    __bf16* o_b    = (__bf16*)alloc((size_t)4096 * 1024 * 2);
    float*  x2     = (float*)alloc((size_t)4096 * 1024 * 4);
    __bf16* vt_b   = (__bf16*)alloc((size_t)32 * 64 * 2048 * 2);
    __bf16* act_b  = qkv_b;  // alias: act over [qkv|o] (dead after o-proj)

    cvt_kernel<<<3072, 256, 0, stream>>>(w_qkv, wqkv_b);
    cvt_kernel<<<1024, 256, 0, stream>>>(w_o, wo_b);
    cvt_kernel<<<8192, 256, 0, stream>>>(w1, w1_b);
    cvt_kernel<<<4096, 256, 0, stream>>>(w2, w2_b);

    rmsnorm_kernel<<<4096, 256, 0, stream>>>(x, g_attn, h_b);
    gemm_nt<0, 4><<<dim3(32, 24), 256, 0, stream>>>(h_b, 1024, wqkv_b, 1024,
                                                    qkv_b, nullptr, nullptr, 1024, 3072);
    vtrans_kernel<<<dim3(32, 32), 256, 0, stream>>>(qkv_b, vt_b);
    attn_kernel<<<dim3(16, 32), 256, 0, stream>>>(qkv_b, vt_b, o_b);
    // o-proj: N=1024 -> 128x64 tiles, 512 blocks (2 blocks/CU)
    gemm_nt<1, 2><<<dim3(32, 16), 256, 0, stream>>>(o_b, 1024, wo_b, 1024,
                                                    nullptr, x2, x, 1024, 1024);
    rmsnorm_kernel<<<4096, 256, 0, stream>>>(x2, g_ff, h_b);
    gemm_nt<2, 4><<<dim3(32, 64), 256, 0, stream>>>(h_b, 1024, w1_b, 1024,
                                                    act_b, nullptr, nullptr, 1024, 4096);
    // ffn2: N=1024 -> 128x64 tiles, 512 blocks (2 blocks/CU)
    gemm_nt<1, 2><<<dim3(32, 16), 256, 0, stream>>>(act_b, 4096, w2_b, 4096,
                                                    nullptr, out, x2, 4096, 1024);
}